// Round 3
// baseline (188.472 us; speedup 1.0000x reference)
//
#include <hip/hip_runtime.h>
#include <hip/hip_bf16.h>

#define B_ 2
#define T_ 2048
#define C_ 1024
#define H_ 16
#define D_ 64

typedef __attribute__((ext_vector_type(8))) short bf16x8;   // MFMA A/B operand (8 bf16)
typedef __attribute__((ext_vector_type(4))) float f32x4;    // MFMA C/D
typedef __attribute__((ext_vector_type(8))) unsigned short u16x8;
typedef __attribute__((ext_vector_type(2))) unsigned int u32x2;
typedef __attribute__((ext_vector_type(4))) unsigned int u32x4;

// compiler-generated bf16 conversion (lowers to v_cvt_pk_bf16_f32 on gfx950)
__device__ __forceinline__ unsigned short bf1(float a) {
    __bf16 x = (__bf16)a;
    return __builtin_bit_cast(unsigned short, x);
}
__device__ __forceinline__ unsigned int pk2(float a, float b) {
    return (unsigned int)bf1(a) | ((unsigned int)bf1(b) << 16);
}

__device__ __forceinline__ void gll16(const void* g, void* l) {
    __builtin_amdgcn_global_load_lds(
        (const __attribute__((address_space(1))) unsigned int*)g,
        (__attribute__((address_space(3))) unsigned int*)l, 16, 0, 0);
}

// ---------------------------------------------------------------------------
// Kernel 0: convert wq(scaled)|wk|wv -> wb[3072][1024] bf16
// ---------------------------------------------------------------------------
__global__ __launch_bounds__(256) void prep_w(
    const float* __restrict__ wq, const float* __restrict__ wk,
    const float* __restrict__ wv, unsigned short* __restrict__ wb)
{
    const int bid = blockIdx.x, tid = threadIdx.x;
    const int rb = bid * 4;   // 4 rows of 1024
    const float* src = (rb < 1024) ? wq + (size_t)rb * 1024
                     : (rb < 2048) ? wk + (size_t)(rb - 1024) * 1024
                                   : wv + (size_t)(rb - 2048) * 1024;
    const float sc = (rb < 1024) ? 0.125f * 1.4426950408889634f : 1.0f;
    const float4* s4 = (const float4*)src;
    u32x2* d = (u32x2*)(wb + (size_t)rb * 1024);
#pragma unroll
    for (int k = 0; k < 4; k++) {
        float4 v = s4[k * 256 + tid];
        u32x2 w;
        w[0] = pk2(v.x * sc, v.y * sc);
        w[1] = pk2(v.z * sc, v.w * sc);
        d[k * 256 + tid] = w;
    }
}

// ---------------------------------------------------------------------------
// Kernel 1: qkv GEMM.  Z[4096,3072] = x[4096,1024](f32) * wb^T(bf16)
// B staged via global_load_lds; A staged f32->bf16 via cvt_pk. BK=64.
// ---------------------------------------------------------------------------
__global__ __launch_bounds__(256) void qkv_gemm(
    const float* __restrict__ x, const unsigned short* __restrict__ wb,
    unsigned short* __restrict__ qkv)
{
    __shared__ __align__(16) unsigned short As[128 * 64];
    __shared__ __align__(16) unsigned short Bs[128 * 64];
    const int tid = threadIdx.x;
    const int lane = tid & 63, wave = tid >> 6;
    const int g = lane >> 4, c16 = lane & 15;
    const int bid = blockIdx.x;
    const int wg = (bid & 7) * 96 + (bid >> 3);   // XCD-chunked swizzle (768 = 8*96)
    const int bm = wg & 31, bn = wg >> 5;
    const int jbase = bn << 7;
    const int which = jbase >> 10;

    const float* xrow = x + ((size_t)(bm << 7) + (tid >> 1)) * C_ + ((tid & 1) << 5);
    const unsigned short* wsrc =
        wb + ((size_t)(bn << 7) + wave * 32 + (lane >> 3)) * C_ + ((lane & 7) << 3);
    unsigned short* asdst = &As[(tid >> 1) * 64 + ((tid & 1) << 5)];

    f32x4 acc[4][4];
#pragma unroll
    for (int i = 0; i < 4; i++)
#pragma unroll
        for (int j = 0; j < 4; j++) acc[i][j] = (f32x4){0.f, 0.f, 0.f, 0.f};

    const int wm = (wave >> 1) << 6, wn = (wave & 1) << 6;

    for (int t = 0; t < 16; ++t) {
        const int k0 = t << 6;
        __syncthreads();
        // stage B via async global->LDS (4 x 1KB per wave)
#pragma unroll
        for (int i = 0; i < 4; i++)
            gll16(wsrc + k0 + i * 8 * C_, &Bs[(wave * 32 + i * 8) * 64]);
        // stage A: 32 f32 -> bf16 per thread
        {
            const float* s = xrow + k0;
            float4 f[8];
#pragma unroll
            for (int i = 0; i < 8; i++) f[i] = *reinterpret_cast<const float4*>(s + i * 4);
            unsigned int pk[16];
#pragma unroll
            for (int i = 0; i < 8; i++) {
                pk[2 * i] = pk2(f[i].x, f[i].y);
                pk[2 * i + 1] = pk2(f[i].z, f[i].w);
            }
#pragma unroll
            for (int i = 0; i < 4; i++) {
                u32x4 w = {pk[4 * i], pk[4 * i + 1], pk[4 * i + 2], pk[4 * i + 3]};
                *reinterpret_cast<u32x4*>(asdst + i * 8) = w;
            }
        }
        __syncthreads();

#pragma unroll
        for (int kk = 0; kk < 2; kk++) {
            bf16x8 af[4], bfv[4];
#pragma unroll
            for (int m = 0; m < 4; m++)
                af[m] = *reinterpret_cast<const bf16x8*>(&As[(wm + m * 16 + c16) * 64 + kk * 32 + g * 8]);
#pragma unroll
            for (int n = 0; n < 4; n++)
                bfv[n] = *reinterpret_cast<const bf16x8*>(&Bs[(wn + n * 16 + c16) * 64 + kk * 32 + g * 8]);
#pragma unroll
            for (int m = 0; m < 4; m++)
#pragma unroll
                for (int n = 0; n < 4; n++)
                    acc[m][n] = __builtin_amdgcn_mfma_f32_16x16x32_bf16(af[m], bfv[n], acc[m][n], 0, 0, 0);
        }
    }

    // epilogue: scatter to qkv[which][b][h][t][d] (q already scaled via wb)
#pragma unroll
    for (int m = 0; m < 4; m++) {
        const int grow = (bm << 7) + wm + m * 16 + (g << 2);
#pragma unroll
        for (int n = 0; n < 4; n++) {
            const int j = jbase + wn + n * 16 + c16;
            const int jj = j & 1023;
            const int h = jj >> 6, d = jj & 63;
#pragma unroll
            for (int r = 0; r < 4; r++) {
                const int row = grow + r;
                const int b = row >> 11, t = row & 2047;
                const size_t off = ((size_t)((which * B_ + b) * H_ + h) * T_ + t) * 64 + d;
                qkv[off] = bf1(acc[m][n][r]);
            }
        }
    }
}

// ---------------------------------------------------------------------------
// Kernel 2: causal flash attention, transposed (S^T / O^T) form.
// ---------------------------------------------------------------------------
__device__ __forceinline__ void attn_tile(
    const unsigned short* __restrict__ Ks, const unsigned short* __restrict__ Vt,
    unsigned short* __restrict__ Psw,
    const bf16x8& qf0, const bf16x8& qf1,
    float& m_run, float& l_run, f32x4* acc,
    int qglob, int s0, bool diag, int g, int c16)
{
    f32x4 sfT[4];
#pragma unroll
    for (int f = 0; f < 4; f++) sfT[f] = (f32x4){0.f, 0.f, 0.f, 0.f};

    __builtin_amdgcn_s_setprio(1);
#pragma unroll
    for (int f = 0; f < 4; f++) {
        const int row = f * 16 + c16;
        const int sw = row & 7;
        bf16x8 k0 = *reinterpret_cast<const bf16x8*>(&Ks[(row << 6) + ((g ^ sw) << 3)]);
        bf16x8 k1 = *reinterpret_cast<const bf16x8*>(&Ks[(row << 6) + (((g + 4) ^ sw) << 3)]);
        sfT[f] = __builtin_amdgcn_mfma_f32_16x16x32_bf16(k0, qf0, sfT[f], 0, 0, 0);
        sfT[f] = __builtin_amdgcn_mfma_f32_16x16x32_bf16(k1, qf1, sfT[f], 0, 0, 0);
    }
    __builtin_amdgcn_s_setprio(0);

    if (diag) {
#pragma unroll
        for (int f = 0; f < 4; f++)
#pragma unroll
            for (int r = 0; r < 4; r++) {
                const int kv = s0 + f * 16 + g * 4 + r;
                if (kv > qglob) sfT[f][r] = -1e30f;
            }
    }

    float mloc = -1e30f;
#pragma unroll
    for (int f = 0; f < 4; f++)
#pragma unroll
        for (int r = 0; r < 4; r++) mloc = fmaxf(mloc, sfT[f][r]);
    mloc = fmaxf(mloc, __shfl_xor(mloc, 16, 64));
    mloc = fmaxf(mloc, __shfl_xor(mloc, 32, 64));
    const float mn = fmaxf(m_run, mloc);
    const float corr = __builtin_amdgcn_exp2f(m_run - mn);
    m_run = mn;
    float ssum = 0.f;
#pragma unroll
    for (int f = 0; f < 4; f++)
#pragma unroll
        for (int r = 0; r < 4; r++) {
            const float pv = __builtin_amdgcn_exp2f(sfT[f][r] - mn);
            sfT[f][r] = pv;
            ssum += pv;
        }
    ssum += __shfl_xor(ssum, 16, 64);
    ssum += __shfl_xor(ssum, 32, 64);
    l_run = l_run * corr + ssum;
#pragma unroll
    for (int fd = 0; fd < 4; fd++)
#pragma unroll
        for (int r = 0; r < 4; r++) acc[fd][r] *= corr;

#pragma unroll
    for (int f = 0; f < 4; f++) {
        u32x2 w;
        w[0] = pk2(sfT[f][0], sfT[f][1]);
        w[1] = pk2(sfT[f][2], sfT[f][3]);
        *reinterpret_cast<u32x2*>(&Psw[c16 * 72 + f * 16 + g * 4]) = w;
    }

    __builtin_amdgcn_s_setprio(1);
#pragma unroll
    for (int ks = 0; ks < 2; ks++) {
        bf16x8 pa = *reinterpret_cast<const bf16x8*>(&Psw[c16 * 72 + ks * 32 + (g << 3)]);
#pragma unroll
        for (int fd = 0; fd < 4; fd++) {
            const int d = fd * 16 + c16;
            bf16x8 vf = *reinterpret_cast<const bf16x8*>(
                &Vt[d * 72 + ((((ks << 2) + g) ^ ((d >> 3) & 7)) << 3)]);
            acc[fd] = __builtin_amdgcn_mfma_f32_16x16x32_bf16(vf, pa, acc[fd], 0, 0, 0);
        }
    }
    __builtin_amdgcn_s_setprio(0);
}

__global__ __launch_bounds__(256) void attn(
    const unsigned short* __restrict__ qkv, unsigned short* __restrict__ y)
{
    __shared__ __align__(16) unsigned short Ks[64 * 64];
    __shared__ __align__(16) unsigned short Vt[64 * 72];
    __shared__ __align__(16) unsigned short Ps[4][16 * 72];
    const int tid = threadIdx.x, lane = tid & 63, wave = tid >> 6;
    const int g = lane >> 4, c16 = lane & 15;
    const int p = blockIdx.x & 15;
    const int bh = blockIdx.x >> 4;
    const int b = bh >> 4, h = bh & 15;
    const size_t headoff = (size_t)(b * H_ + h) * T_ * 64;
    const size_t QSZ = (size_t)B_ * H_ * T_ * 64;
    const unsigned short* qp = qkv + headoff;
    const unsigned short* kp = qkv + QSZ + headoff;
    const unsigned short* vp = qkv + 2 * QSZ + headoff;

    const int tA = p, tB = 31 - p;
    const int qbaseA = (tA << 6) + wave * 16, qbaseB = (tB << 6) + wave * 16;

    bf16x8 qfA[2], qfB[2];
    {
        const size_t ra = (size_t)(qbaseA + c16) * 64, rb = (size_t)(qbaseB + c16) * 64;
        qfA[0] = *reinterpret_cast<const bf16x8*>(qp + ra + g * 8);
        qfA[1] = *reinterpret_cast<const bf16x8*>(qp + ra + 32 + g * 8);
        qfB[0] = *reinterpret_cast<const bf16x8*>(qp + rb + g * 8);
        qfB[1] = *reinterpret_cast<const bf16x8*>(qp + rb + 32 + g * 8);
    }

    float mA = -1e30f, lA = 0.f, mB = -1e30f, lB = 0.f;
    f32x4 accA[4], accB[4];
#pragma unroll
    for (int i = 0; i < 4; i++) {
        accA[i] = (f32x4){0.f, 0.f, 0.f, 0.f};
        accB[i] = (f32x4){0.f, 0.f, 0.f, 0.f};
    }

    const int krow = tid >> 2, kc2 = (tid & 3) << 1;
    const int vr2 = (tid >> 3) << 1, vds = (tid & 7) << 3;

    const int nt = 32 - p;
    for (int it = 0; it < nt; ++it) {
        const int s0 = it << 6;
        __syncthreads();
        {
            const unsigned short* src = kp + (size_t)(s0 + krow) * 64 + (kc2 << 3);
            u16x8 a0 = *reinterpret_cast<const u16x8*>(src);
            u16x8 a1 = *reinterpret_cast<const u16x8*>(src + 8);
            const int sw = krow & 7;
            *reinterpret_cast<u16x8*>(&Ks[(krow << 6) + ((kc2 ^ sw) << 3)]) = a0;
            *reinterpret_cast<u16x8*>(&Ks[(krow << 6) + (((kc2 + 1) ^ sw) << 3)]) = a1;
        }
        {
            const unsigned short* sp = vp + (size_t)(s0 + vr2) * 64 + vds;
            u16x8 v0 = *reinterpret_cast<const u16x8*>(sp);
            u16x8 v1 = *reinterpret_cast<const u16x8*>(sp + 64);
#pragma unroll
            for (int i = 0; i < 8; i++) {
                const int d = vds + i;
                const unsigned int w = (unsigned int)v0[i] | ((unsigned int)v1[i] << 16);
                const int idx = d * 72 + ((((vr2 >> 3) ^ ((d >> 3) & 7)) << 3) | (vr2 & 7));
                *reinterpret_cast<unsigned int*>(&Vt[idx]) = w;
            }
        }
        __syncthreads();

        attn_tile(Ks, Vt, Ps[wave], qfB[0], qfB[1], mB, lB, accB,
                  qbaseB + c16, s0, it == tB, g, c16);
        if (it <= tA)
            attn_tile(Ks, Vt, Ps[wave], qfA[0], qfA[1], mA, lA, accA,
                      qbaseA + c16, s0, it == tA, g, c16);
    }

    const float liA = 1.0f / lA, liB = 1.0f / lB;
#pragma unroll
    for (int fd = 0; fd < 4; fd++) {
        u32x2 wa, wb2;
        wa[0] = pk2(accA[fd][0] * liA, accA[fd][1] * liA);
        wa[1] = pk2(accA[fd][2] * liA, accA[fd][3] * liA);
        wb2[0] = pk2(accB[fd][0] * liB, accB[fd][1] * liB);
        wb2[1] = pk2(accB[fd][2] * liB, accB[fd][3] * liB);
        const size_t ca = ((size_t)b * T_ + qbaseA + c16) * 1024 + h * 64 + fd * 16 + g * 4;
        const size_t cb = ((size_t)b * T_ + qbaseB + c16) * 1024 + h * 64 + fd * 16 + g * 4;
        *reinterpret_cast<u32x2*>(&y[ca]) = wa;
        *reinterpret_cast<u32x2*>(&y[cb]) = wb2;
    }
}

// ---------------------------------------------------------------------------
// Kernel 3: out = y[4096,1024](bf16) @ w_o[1024,1024](f32) -> f32
// A via global_load_lds; B transpose-staged with cvt_pk. BK=32.
// ---------------------------------------------------------------------------
__global__ __launch_bounds__(256) void out_proj(
    const unsigned short* __restrict__ y, const float* __restrict__ wo,
    float* __restrict__ out)
{
    __shared__ __align__(16) unsigned short As[128 * 32];
    __shared__ __align__(16) unsigned short Bt[128 * 40];
    const int tid = threadIdx.x;
    const int lane = tid & 63, wave = tid >> 6;
    const int g = lane >> 4, c16 = lane & 15;
    const int bid = blockIdx.x;
    const int wg = (bid & 7) * 32 + (bid >> 3);   // XCD swizzle (256 = 8*32)
    const int bm = wg & 31, bn = wg >> 5;
    const int wm = (wave >> 1) << 6, wn = (wave & 1) << 6;

    f32x4 acc[4][4];
#pragma unroll
    for (int i = 0; i < 4; i++)
#pragma unroll
        for (int j = 0; j < 4; j++) acc[i][j] = (f32x4){0.f, 0.f, 0.f, 0.f};

    const unsigned short* ysrc =
        y + ((size_t)(bm << 7) + wave * 32 + (lane >> 2)) * 1024 + ((lane & 3) << 3);
    const int kk2 = (tid & 15) << 1, nseg = (tid >> 4) << 3;

    for (int k0 = 0; k0 < 1024; k0 += 32) {
        __syncthreads();
#pragma unroll
        for (int i = 0; i < 2; i++)
            gll16(ysrc + k0 + i * 16 * 1024, &As[(wave * 32 + i * 16) * 32]);
        {
            const float* sp = wo + (size_t)(k0 + kk2) * 1024 + (bn << 7) + nseg;
            float4 a0 = *reinterpret_cast<const float4*>(sp);
            float4 a1 = *reinterpret_cast<const float4*>(sp + 4);
            float4 b0 = *reinterpret_cast<const float4*>(sp + 1024);
            float4 b1 = *reinterpret_cast<const float4*>(sp + 1028);
            float va[8] = {a0.x, a0.y, a0.z, a0.w, a1.x, a1.y, a1.z, a1.w};
            float vb[8] = {b0.x, b0.y, b0.z, b0.w, b1.x, b1.y, b1.z, b1.w};
#pragma unroll
            for (int i = 0; i < 8; i++)
                *reinterpret_cast<unsigned int*>(&Bt[(nseg + i) * 40 + kk2]) = pk2(va[i], vb[i]);
        }
        __syncthreads();

        bf16x8 af[4], bfr[4];
#pragma unroll
        for (int m = 0; m < 4; m++)
            af[m] = *reinterpret_cast<const bf16x8*>(&As[(wm + m * 16 + c16) * 32 + g * 8]);
#pragma unroll
        for (int n = 0; n < 4; n++)
            bfr[n] = *reinterpret_cast<const bf16x8*>(&Bt[(wn + n * 16 + c16) * 40 + g * 8]);
#pragma unroll
        for (int m = 0; m < 4; m++)
#pragma unroll
            for (int n = 0; n < 4; n++)
                acc[m][n] = __builtin_amdgcn_mfma_f32_16x16x32_bf16(af[m], bfr[n], acc[m][n], 0, 0, 0);
    }

#pragma unroll
    for (int m = 0; m < 4; m++) {
        const int grow = (bm << 7) + wm + m * 16 + (g << 2);
#pragma unroll
        for (int n = 0; n < 4; n++) {
            const int gcol = (bn << 7) + wn + n * 16 + c16;
#pragma unroll
            for (int r = 0; r < 4; r++)
                out[(size_t)(grow + r) * 1024 + gcol] = acc[m][n][r];
        }
    }
}

extern "C" void kernel_launch(void* const* d_in, const int* in_sizes, int n_in,
                              void* d_out, int out_size, void* d_ws, size_t ws_size,
                              hipStream_t stream) {
    const float* x  = (const float*)d_in[0];
    const float* wq = (const float*)d_in[1];
    const float* wk = (const float*)d_in[2];
    const float* wv = (const float*)d_in[3];
    const float* wo = (const float*)d_in[4];
    float* out = (float*)d_out;

    // ws layout (32 MB): [0,8MB): wb (6MB) then reused as y (8MB); [8MB,32MB): qkv
    unsigned short* wb  = (unsigned short*)d_ws;
    unsigned short* y   = (unsigned short*)d_ws;
    unsigned short* qkv = (unsigned short*)d_ws + (size_t)4 * 1024 * 1024;

    prep_w<<<dim3(768), 256, 0, stream>>>(wq, wk, wv, wb);
    qkv_gemm<<<dim3(768), 256, 0, stream>>>(x, wb, qkv);
    attn<<<dim3(16 * B_ * H_), 256, 0, stream>>>(qkv, y);
    out_proj<<<dim3(256), 256, 0, stream>>>(y, wo, out);
}

// Round 4
// 157.854 us; speedup vs baseline: 1.1940x; 1.1940x over previous
//
#include <hip/hip_runtime.h>
#include <hip/hip_bf16.h>

#define B_ 2
#define T_ 2048
#define C_ 1024
#define H_ 16
#define D_ 64

typedef __attribute__((ext_vector_type(8))) short bf16x8;   // MFMA A/B operand (8 bf16)
typedef __attribute__((ext_vector_type(4))) float f32x4;    // MFMA C/D
typedef __attribute__((ext_vector_type(8))) unsigned short u16x8;
typedef __attribute__((ext_vector_type(2))) unsigned int u32x2;
typedef __attribute__((ext_vector_type(4))) unsigned int u32x4;

__device__ __forceinline__ unsigned short bf1(float a) {
    __bf16 x = (__bf16)a;
    return __builtin_bit_cast(unsigned short, x);
}
__device__ __forceinline__ unsigned int pk2(float a, float b) {
    return (unsigned int)bf1(a) | ((unsigned int)bf1(b) << 16);
}

__device__ __forceinline__ void gll16(const void* g, void* l) {
    __builtin_amdgcn_global_load_lds(
        (const __attribute__((address_space(1))) unsigned int*)g,
        (__attribute__((address_space(3))) unsigned int*)l, 16, 0, 0);
}

// ---------------------------------------------------------------------------
// Kernel 0a: convert wq(scaled)|wk|wv -> wb[3072][1024] bf16
// ---------------------------------------------------------------------------
__global__ __launch_bounds__(256) void prep_w(
    const float* __restrict__ wq, const float* __restrict__ wk,
    const float* __restrict__ wv, unsigned short* __restrict__ wb)
{
    const int bid = blockIdx.x, tid = threadIdx.x;
    const int rb = bid * 4;
    const float* src = (rb < 1024) ? wq + (size_t)rb * 1024
                     : (rb < 2048) ? wk + (size_t)(rb - 1024) * 1024
                                   : wv + (size_t)(rb - 2048) * 1024;
    const float sc = (rb < 1024) ? 0.125f * 1.4426950408889634f : 1.0f;
    const float4* s4 = (const float4*)src;
    u32x2* d = (u32x2*)(wb + (size_t)rb * 1024);
#pragma unroll
    for (int k = 0; k < 4; k++) {
        float4 v = s4[k * 256 + tid];
        u32x2 w;
        w[0] = pk2(v.x * sc, v.y * sc);
        w[1] = pk2(v.z * sc, v.w * sc);
        d[k * 256 + tid] = w;
    }
}

// ---------------------------------------------------------------------------
// Kernel 0b: wt[n][k] = bf16(wo[k][n])  (tiled transpose, runs after attn)
// ---------------------------------------------------------------------------
__global__ __launch_bounds__(256) void prep_wo(
    const float* __restrict__ wo, unsigned short* __restrict__ wt)
{
    __shared__ unsigned short tile[64][72];
    const int tk = (blockIdx.x & 15) << 6, tn = (blockIdx.x >> 4) << 6;
    const int r = threadIdx.x >> 2, cb = (threadIdx.x & 3) << 4;
#pragma unroll
    for (int j = 0; j < 4; j++) {
        float4 v = *reinterpret_cast<const float4*>(
            wo + (size_t)(tk + r) * 1024 + tn + cb + j * 4);
        u32x2 w;
        w[0] = pk2(v.x, v.y);
        w[1] = pk2(v.z, v.w);
        *reinterpret_cast<u32x2*>(&tile[r][cb + j * 4]) = w;
    }
    __syncthreads();
    unsigned short buf[16];
#pragma unroll
    for (int j = 0; j < 16; j++) buf[j] = tile[cb + j][r];
    unsigned short* dst = wt + (size_t)(tn + r) * 1024 + tk + cb;
    *reinterpret_cast<u16x8*>(dst) = *reinterpret_cast<u16x8*>(buf);
    *reinterpret_cast<u16x8*>(dst + 8) = *reinterpret_cast<u16x8*>(buf + 8);
}

// ---------------------------------------------------------------------------
// Kernel 1: qkv GEMM.  Z[4096,3072] = x[4096,1024](f32) * wb^T(bf16)
// B via gll16 w/ pre-swizzled source; A reg-staged cvt_pk w/ swizzled write.
// All LDS accesses XOR-chunk swizzled -> <=2-way (free). BK=64.
// ---------------------------------------------------------------------------
__global__ __launch_bounds__(256) void qkv_gemm(
    const float* __restrict__ x, const unsigned short* __restrict__ wb,
    unsigned short* __restrict__ qkv)
{
    __shared__ __align__(16) unsigned short As[128 * 64];
    __shared__ __align__(16) unsigned short Bs[128 * 64];
    const int tid = threadIdx.x;
    const int lane = tid & 63, wave = tid >> 6;
    const int g = lane >> 4, c16 = lane & 15;
    // M-chunked XCD mapping: each XCD owns 4 bm x 24 bn (x tile stays in its L2)
    const int xcd = blockIdx.x & 7, idx = blockIdx.x >> 3;
    const int bm = (xcd << 2) + idx / 24, bn = idx % 24;
    const int jbase = bn << 7;
    const int which = jbase >> 10;

    // B source: pre-swizzled chunk (l&7)^(l>>3) (wave-invariant row&7 = l>>3)
    const unsigned short* bsrc = wb + ((size_t)(bn << 7) + wave * 32 + (lane >> 3)) * C_
                                    + (((lane & 7) ^ (lane >> 3)) << 3);
    // A: f32 x, reg-staged; swizzled ds_write
    const int arow = tid >> 1;
    const float* xrow = x + ((size_t)(bm << 7) + arow) * C_ + ((tid & 1) << 5);
    unsigned short* adst = &As[arow << 6];
    const int asw = arow & 7;
    const int acb = (tid & 1) << 2;   // logical chunk base 0 or 4

    f32x4 acc[4][4];
#pragma unroll
    for (int i = 0; i < 4; i++)
#pragma unroll
        for (int j = 0; j < 4; j++) acc[i][j] = (f32x4){0.f, 0.f, 0.f, 0.f};

    const int wm = (wave >> 1) << 6, wn = (wave & 1) << 6;

    for (int t = 0; t < 16; ++t) {
        const int k0 = t << 6;
        __syncthreads();
#pragma unroll
        for (int i = 0; i < 4; i++)
            gll16(bsrc + k0 + i * 8 * C_, &Bs[(wave * 32 + i * 8) << 6]);
        {
            const float* s = xrow + k0;
            float4 f[8];
#pragma unroll
            for (int i = 0; i < 8; i++) f[i] = *reinterpret_cast<const float4*>(s + i * 4);
            unsigned int pk[16];
#pragma unroll
            for (int i = 0; i < 8; i++) {
                pk[2 * i] = pk2(f[i].x, f[i].y);
                pk[2 * i + 1] = pk2(f[i].z, f[i].w);
            }
#pragma unroll
            for (int i = 0; i < 4; i++) {
                u32x4 w = {pk[4 * i], pk[4 * i + 1], pk[4 * i + 2], pk[4 * i + 3]};
                *reinterpret_cast<u32x4*>(adst + (((acb + i) ^ asw) << 3)) = w;
            }
        }
        __syncthreads();

#pragma unroll
        for (int kk = 0; kk < 2; kk++) {
            bf16x8 af[4], bfv[4];
#pragma unroll
            for (int m = 0; m < 4; m++) {
                const int row = wm + m * 16 + c16;
                af[m] = *reinterpret_cast<const bf16x8*>(
                    &As[(row << 6) + ((((kk << 2) + g) ^ (c16 & 7)) << 3)]);
            }
#pragma unroll
            for (int n = 0; n < 4; n++) {
                const int row = wn + n * 16 + c16;
                bfv[n] = *reinterpret_cast<const bf16x8*>(
                    &Bs[(row << 6) + ((((kk << 2) + g) ^ (c16 & 7)) << 3)]);
            }
#pragma unroll
            for (int m = 0; m < 4; m++)
#pragma unroll
                for (int n = 0; n < 4; n++)
                    acc[m][n] = __builtin_amdgcn_mfma_f32_16x16x32_bf16(af[m], bfv[n], acc[m][n], 0, 0, 0);
        }
    }

#pragma unroll
    for (int m = 0; m < 4; m++) {
        const int grow = (bm << 7) + wm + m * 16 + (g << 2);
#pragma unroll
        for (int n = 0; n < 4; n++) {
            const int j = jbase + wn + n * 16 + c16;
            const int jj = j & 1023;
            const int h = jj >> 6, d = jj & 63;
#pragma unroll
            for (int r = 0; r < 4; r++) {
                const int row = grow + r;
                const int b = row >> 11, t = row & 2047;
                const size_t off = ((size_t)((which * B_ + b) * H_ + h) * T_ + t) * 64 + d;
                qkv[off] = bf1(acc[m][n][r]);
            }
        }
    }
}

// ---------------------------------------------------------------------------
// Kernel 2: causal flash attention, transposed (S^T / O^T) form.
// ---------------------------------------------------------------------------
__device__ __forceinline__ void attn_tile(
    const unsigned short* __restrict__ Ks, const unsigned short* __restrict__ Vt,
    unsigned short* __restrict__ Psw,
    const bf16x8& qf0, const bf16x8& qf1,
    float& m_run, float& l_run, f32x4* acc,
    int qglob, int s0, bool diag, int g, int c16)
{
    f32x4 sfT[4];
#pragma unroll
    for (int f = 0; f < 4; f++) sfT[f] = (f32x4){0.f, 0.f, 0.f, 0.f};

    __builtin_amdgcn_s_setprio(1);
#pragma unroll
    for (int f = 0; f < 4; f++) {
        const int row = f * 16 + c16;
        const int sw = row & 7;
        bf16x8 k0 = *reinterpret_cast<const bf16x8*>(&Ks[(row << 6) + ((g ^ sw) << 3)]);
        bf16x8 k1 = *reinterpret_cast<const bf16x8*>(&Ks[(row << 6) + (((g + 4) ^ sw) << 3)]);
        sfT[f] = __builtin_amdgcn_mfma_f32_16x16x32_bf16(k0, qf0, sfT[f], 0, 0, 0);
        sfT[f] = __builtin_amdgcn_mfma_f32_16x16x32_bf16(k1, qf1, sfT[f], 0, 0, 0);
    }
    __builtin_amdgcn_s_setprio(0);

    if (diag) {
#pragma unroll
        for (int f = 0; f < 4; f++)
#pragma unroll
            for (int r = 0; r < 4; r++) {
                const int kv = s0 + f * 16 + g * 4 + r;
                if (kv > qglob) sfT[f][r] = -1e30f;
            }
    }

    float mloc = -1e30f;
#pragma unroll
    for (int f = 0; f < 4; f++)
#pragma unroll
        for (int r = 0; r < 4; r++) mloc = fmaxf(mloc, sfT[f][r]);
    mloc = fmaxf(mloc, __shfl_xor(mloc, 16, 64));
    mloc = fmaxf(mloc, __shfl_xor(mloc, 32, 64));
    const float mn = fmaxf(m_run, mloc);
    const float corr = __builtin_amdgcn_exp2f(m_run - mn);
    m_run = mn;
    float ssum = 0.f;
#pragma unroll
    for (int f = 0; f < 4; f++)
#pragma unroll
        for (int r = 0; r < 4; r++) {
            const float pv = __builtin_amdgcn_exp2f(sfT[f][r] - mn);
            sfT[f][r] = pv;
            ssum += pv;
        }
    ssum += __shfl_xor(ssum, 16, 64);
    ssum += __shfl_xor(ssum, 32, 64);
    l_run = l_run * corr + ssum;
#pragma unroll
    for (int fd = 0; fd < 4; fd++)
#pragma unroll
        for (int r = 0; r < 4; r++) acc[fd][r] *= corr;

#pragma unroll
    for (int f = 0; f < 4; f++) {
        u32x2 w;
        w[0] = pk2(sfT[f][0], sfT[f][1]);
        w[1] = pk2(sfT[f][2], sfT[f][3]);
        *reinterpret_cast<u32x2*>(&Psw[c16 * 72 + f * 16 + g * 4]) = w;
    }

    __builtin_amdgcn_s_setprio(1);
#pragma unroll
    for (int ks = 0; ks < 2; ks++) {
        bf16x8 pa = *reinterpret_cast<const bf16x8*>(&Psw[c16 * 72 + ks * 32 + (g << 3)]);
#pragma unroll
        for (int fd = 0; fd < 4; fd++) {
            const int d = fd * 16 + c16;
            bf16x8 vf = *reinterpret_cast<const bf16x8*>(
                &Vt[d * 72 + ((((ks << 2) + g) ^ ((d >> 3) & 7)) << 3)]);
            acc[fd] = __builtin_amdgcn_mfma_f32_16x16x32_bf16(vf, pa, acc[fd], 0, 0, 0);
        }
    }
    __builtin_amdgcn_s_setprio(0);
}

__global__ __launch_bounds__(256) void attn(
    const unsigned short* __restrict__ qkv, unsigned short* __restrict__ y)
{
    __shared__ __align__(16) unsigned short Ks[64 * 64];
    __shared__ __align__(16) unsigned short Vt[64 * 72];
    __shared__ __align__(16) unsigned short Ps[4][16 * 72];
    const int tid = threadIdx.x, lane = tid & 63, wave = tid >> 6;
    const int g = lane >> 4, c16 = lane & 15;
    const int p = blockIdx.x & 15;
    const int bh = blockIdx.x >> 4;
    const int b = bh >> 4, h = bh & 15;
    const size_t headoff = (size_t)(b * H_ + h) * T_ * 64;
    const size_t QSZ = (size_t)B_ * H_ * T_ * 64;
    const unsigned short* qp = qkv + headoff;
    const unsigned short* kp = qkv + QSZ + headoff;
    const unsigned short* vp = qkv + 2 * QSZ + headoff;

    const int tA = p, tB = 31 - p;
    const int qbaseA = (tA << 6) + wave * 16, qbaseB = (tB << 6) + wave * 16;

    bf16x8 qfA[2], qfB[2];
    {
        const size_t ra = (size_t)(qbaseA + c16) * 64, rb = (size_t)(qbaseB + c16) * 64;
        qfA[0] = *reinterpret_cast<const bf16x8*>(qp + ra + g * 8);
        qfA[1] = *reinterpret_cast<const bf16x8*>(qp + ra + 32 + g * 8);
        qfB[0] = *reinterpret_cast<const bf16x8*>(qp + rb + g * 8);
        qfB[1] = *reinterpret_cast<const bf16x8*>(qp + rb + 32 + g * 8);
    }

    float mA = -1e30f, lA = 0.f, mB = -1e30f, lB = 0.f;
    f32x4 accA[4], accB[4];
#pragma unroll
    for (int i = 0; i < 4; i++) {
        accA[i] = (f32x4){0.f, 0.f, 0.f, 0.f};
        accB[i] = (f32x4){0.f, 0.f, 0.f, 0.f};
    }

    const int krow = tid >> 2, kc2 = (tid & 3) << 1;
    const int vr2 = (tid >> 3) << 1, vds = (tid & 7) << 3;

    const int nt = 32 - p;
    for (int it = 0; it < nt; ++it) {
        const int s0 = it << 6;
        __syncthreads();
        {
            const unsigned short* src = kp + (size_t)(s0 + krow) * 64 + (kc2 << 3);
            u16x8 a0 = *reinterpret_cast<const u16x8*>(src);
            u16x8 a1 = *reinterpret_cast<const u16x8*>(src + 8);
            const int sw = krow & 7;
            *reinterpret_cast<u16x8*>(&Ks[(krow << 6) + ((kc2 ^ sw) << 3)]) = a0;
            *reinterpret_cast<u16x8*>(&Ks[(krow << 6) + (((kc2 + 1) ^ sw) << 3)]) = a1;
        }
        {
            const unsigned short* sp = vp + (size_t)(s0 + vr2) * 64 + vds;
            u16x8 v0 = *reinterpret_cast<const u16x8*>(sp);
            u16x8 v1 = *reinterpret_cast<const u16x8*>(sp + 64);
#pragma unroll
            for (int i = 0; i < 8; i++) {
                const int d = vds + i;
                const unsigned int w = (unsigned int)v0[i] | ((unsigned int)v1[i] << 16);
                const int idx = d * 72 + ((((vr2 >> 3) ^ ((d >> 3) & 7)) << 3) | (vr2 & 7));
                *reinterpret_cast<unsigned int*>(&Vt[idx]) = w;
            }
        }
        __syncthreads();

        attn_tile(Ks, Vt, Ps[wave], qfB[0], qfB[1], mB, lB, accB,
                  qbaseB + c16, s0, it == tB, g, c16);
        if (it <= tA)
            attn_tile(Ks, Vt, Ps[wave], qfA[0], qfA[1], mA, lA, accA,
                      qbaseA + c16, s0, it == tA, g, c16);
    }

    const float liA = 1.0f / lA, liB = 1.0f / lB;
#pragma unroll
    for (int fd = 0; fd < 4; fd++) {
        u32x2 wa, wb2;
        wa[0] = pk2(accA[fd][0] * liA, accA[fd][1] * liA);
        wa[1] = pk2(accA[fd][2] * liA, accA[fd][3] * liA);
        wb2[0] = pk2(accB[fd][0] * liB, accB[fd][1] * liB);
        wb2[1] = pk2(accB[fd][2] * liB, accB[fd][3] * liB);
        const size_t ca = ((size_t)b * T_ + qbaseA + c16) * 1024 + h * 64 + fd * 16 + g * 4;
        const size_t cb = ((size_t)b * T_ + qbaseB + c16) * 1024 + h * 64 + fd * 16 + g * 4;
        *reinterpret_cast<u32x2*>(&y[ca]) = wa;
        *reinterpret_cast<u32x2*>(&y[cb]) = wb2;
    }
}

// ---------------------------------------------------------------------------
// Kernel 3: out[4096,1024] = y(bf16) @ wt^T(bf16)  (wt = wo^T), both via gll16
// ---------------------------------------------------------------------------
__global__ __launch_bounds__(256) void out_proj(
    const unsigned short* __restrict__ y, const unsigned short* __restrict__ wt,
    float* __restrict__ out)
{
    __shared__ __align__(16) unsigned short As[128 * 64];
    __shared__ __align__(16) unsigned short Bs[128 * 64];
    const int tid = threadIdx.x;
    const int lane = tid & 63, wave = tid >> 6;
    const int g = lane >> 4, c16 = lane & 15;
    const int xcd = blockIdx.x & 7, idx = blockIdx.x >> 3;   // 256 = 8 * (4 bm * 8 bn)
    const int bm = (xcd << 2) + (idx >> 3), bn = idx & 7;
    const int wm = (wave >> 1) << 6, wn = (wave & 1) << 6;

    const int swc = ((lane & 7) ^ (lane >> 3)) << 3;
    const unsigned short* ysrc = y + ((size_t)(bm << 7) + wave * 32 + (lane >> 3)) * 1024 + swc;
    const unsigned short* wsrc = wt + ((size_t)(bn << 7) + wave * 32 + (lane >> 3)) * 1024 + swc;

    f32x4 acc[4][4];
#pragma unroll
    for (int i = 0; i < 4; i++)
#pragma unroll
        for (int j = 0; j < 4; j++) acc[i][j] = (f32x4){0.f, 0.f, 0.f, 0.f};

    for (int t = 0; t < 16; ++t) {
        const int k0 = t << 6;
        __syncthreads();
#pragma unroll
        for (int i = 0; i < 4; i++)
            gll16(ysrc + k0 + i * 8 * 1024, &As[(wave * 32 + i * 8) << 6]);
#pragma unroll
        for (int i = 0; i < 4; i++)
            gll16(wsrc + k0 + i * 8 * 1024, &Bs[(wave * 32 + i * 8) << 6]);
        __syncthreads();

#pragma unroll
        for (int kk = 0; kk < 2; kk++) {
            bf16x8 af[4], bfr[4];
#pragma unroll
            for (int m = 0; m < 4; m++) {
                const int row = wm + m * 16 + c16;
                af[m] = *reinterpret_cast<const bf16x8*>(
                    &As[(row << 6) + ((((kk << 2) + g) ^ (c16 & 7)) << 3)]);
            }
#pragma unroll
            for (int n = 0; n < 4; n++) {
                const int row = wn + n * 16 + c16;
                bfr[n] = *reinterpret_cast<const bf16x8*>(
                    &Bs[(row << 6) + ((((kk << 2) + g) ^ (c16 & 7)) << 3)]);
            }
#pragma unroll
            for (int m = 0; m < 4; m++)
#pragma unroll
                for (int n = 0; n < 4; n++)
                    acc[m][n] = __builtin_amdgcn_mfma_f32_16x16x32_bf16(af[m], bfr[n], acc[m][n], 0, 0, 0);
        }
    }

#pragma unroll
    for (int m = 0; m < 4; m++) {
        const int grow = (bm << 7) + wm + m * 16 + (g << 2);
#pragma unroll
        for (int n = 0; n < 4; n++) {
            const int gcol = (bn << 7) + wn + n * 16 + c16;
#pragma unroll
            for (int r = 0; r < 4; r++)
                out[(size_t)(grow + r) * 1024 + gcol] = acc[m][n][r];
        }
    }
}

extern "C" void kernel_launch(void* const* d_in, const int* in_sizes, int n_in,
                              void* d_out, int out_size, void* d_ws, size_t ws_size,
                              hipStream_t stream) {
    const float* x  = (const float*)d_in[0];
    const float* wq = (const float*)d_in[1];
    const float* wk = (const float*)d_in[2];
    const float* wv = (const float*)d_in[3];
    const float* wo = (const float*)d_in[4];
    float* out = (float*)d_out;

    // ws layout (32 MB):
    //   [0,6MB)  wb   (dead after qkv_gemm)    -> y [0,8MB) reuses it (attn)
    //   [8,32MB) qkv  (dead after attn)        -> wt [8,10MB) reuses it (prep_wo)
    unsigned short* wb  = (unsigned short*)d_ws;
    unsigned short* y   = (unsigned short*)d_ws;
    unsigned short* qkv = (unsigned short*)d_ws + (size_t)4 * 1024 * 1024;
    unsigned short* wt  = qkv;

    prep_w<<<dim3(768), 256, 0, stream>>>(wq, wk, wv, wb);
    qkv_gemm<<<dim3(768), 256, 0, stream>>>(x, wb, qkv);
    attn<<<dim3(16 * B_ * H_), 256, 0, stream>>>(qkv, y);
    prep_wo<<<dim3(256), 256, 0, stream>>>(wo, wt);
    out_proj<<<dim3(256), 256, 0, stream>>>(y, wt, out);
}

// Round 5
// 128.903 us; speedup vs baseline: 1.4621x; 1.2246x over previous
//
#include <hip/hip_runtime.h>
#include <hip/hip_bf16.h>

#define B_ 2
#define T_ 2048
#define C_ 1024
#define H_ 16
#define D_ 64

typedef __attribute__((ext_vector_type(8))) short bf16x8;   // MFMA A/B operand (8 bf16)
typedef __attribute__((ext_vector_type(4))) float f32x4;    // MFMA C/D
typedef __attribute__((ext_vector_type(8))) unsigned short u16x8;
typedef __attribute__((ext_vector_type(2))) unsigned int u32x2;
typedef __attribute__((ext_vector_type(4))) unsigned int u32x4;

__device__ __forceinline__ unsigned short bf1(float a) {
    __bf16 x = (__bf16)a;
    return __builtin_bit_cast(unsigned short, x);
}
__device__ __forceinline__ unsigned int pk2(float a, float b) {
    return (unsigned int)bf1(a) | ((unsigned int)bf1(b) << 16);
}

__device__ __forceinline__ void gll16(const void* g, void* l) {
    __builtin_amdgcn_global_load_lds(
        (const __attribute__((address_space(1))) unsigned int*)g,
        (__attribute__((address_space(3))) unsigned int*)l, 16, 0, 0);
}

// ---------------------------------------------------------------------------
// Kernel 0a: x[4096,1024] f32 -> xb bf16 (xb lives in d_out, dead until out_proj)
// ---------------------------------------------------------------------------
__global__ __launch_bounds__(256) void prep_x(
    const float* __restrict__ x, unsigned short* __restrict__ xb)
{
    const size_t i = ((size_t)blockIdx.x * 256 + threadIdx.x) * 16;
    float4 f0 = *reinterpret_cast<const float4*>(x + i);
    float4 f1 = *reinterpret_cast<const float4*>(x + i + 4);
    float4 f2 = *reinterpret_cast<const float4*>(x + i + 8);
    float4 f3 = *reinterpret_cast<const float4*>(x + i + 12);
    u32x4 a = {pk2(f0.x, f0.y), pk2(f0.z, f0.w), pk2(f1.x, f1.y), pk2(f1.z, f1.w)};
    u32x4 b = {pk2(f2.x, f2.y), pk2(f2.z, f2.w), pk2(f3.x, f3.y), pk2(f3.z, f3.w)};
    *reinterpret_cast<u32x4*>(xb + i) = a;
    *reinterpret_cast<u32x4*>(xb + i + 8) = b;
}

// ---------------------------------------------------------------------------
// Kernel 0b: convert wq(scaled)|wk|wv -> wb[3072][1024] bf16
// ---------------------------------------------------------------------------
__global__ __launch_bounds__(256) void prep_w(
    const float* __restrict__ wq, const float* __restrict__ wk,
    const float* __restrict__ wv, unsigned short* __restrict__ wb)
{
    const int bid = blockIdx.x, tid = threadIdx.x;
    const int rb = bid * 4;
    const float* src = (rb < 1024) ? wq + (size_t)rb * 1024
                     : (rb < 2048) ? wk + (size_t)(rb - 1024) * 1024
                                   : wv + (size_t)(rb - 2048) * 1024;
    const float sc = (rb < 1024) ? 0.125f * 1.4426950408889634f : 1.0f;
    const float4* s4 = (const float4*)src;
    u32x2* d = (u32x2*)(wb + (size_t)rb * 1024);
#pragma unroll
    for (int k = 0; k < 4; k++) {
        float4 v = s4[k * 256 + tid];
        u32x2 w;
        w[0] = pk2(v.x * sc, v.y * sc);
        w[1] = pk2(v.z * sc, v.w * sc);
        d[k * 256 + tid] = w;
    }
}

// ---------------------------------------------------------------------------
// Kernel 0c: wt[n][k] = bf16(wo[k][n])  (tiled transpose, runs after attn)
// ---------------------------------------------------------------------------
__global__ __launch_bounds__(256) void prep_wo(
    const float* __restrict__ wo, unsigned short* __restrict__ wt)
{
    __shared__ unsigned short tile[64][72];
    const int tk = (blockIdx.x & 15) << 6, tn = (blockIdx.x >> 4) << 6;
    const int r = threadIdx.x >> 2, cb = (threadIdx.x & 3) << 4;
#pragma unroll
    for (int j = 0; j < 4; j++) {
        float4 v = *reinterpret_cast<const float4*>(
            wo + (size_t)(tk + r) * 1024 + tn + cb + j * 4);
        u32x2 w;
        w[0] = pk2(v.x, v.y);
        w[1] = pk2(v.z, v.w);
        *reinterpret_cast<u32x2*>(&tile[r][cb + j * 4]) = w;
    }
    __syncthreads();
    unsigned short buf[16];
#pragma unroll
    for (int j = 0; j < 16; j++) buf[j] = tile[cb + j][r];
    unsigned short* dst = wt + (size_t)(tn + r) * 1024 + tk + cb;
    *reinterpret_cast<u16x8*>(dst) = *reinterpret_cast<u16x8*>(buf);
    *reinterpret_cast<u16x8*>(dst + 8) = *reinterpret_cast<u16x8*>(buf + 8);
}

// ---------------------------------------------------------------------------
// Kernel 1: qkv GEMM.  Z[4096,3072] = xb[4096,1024](bf16) * wb^T(bf16)
// Both operands via gll16 w/ pre-swizzled source; 2-phase LDS double-buffer
// (one barrier per K-step, gll16 latency overlaps MFMA). BK=64.
// ---------------------------------------------------------------------------
__global__ __launch_bounds__(256) void qkv_gemm(
    const unsigned short* __restrict__ xb, const unsigned short* __restrict__ wb,
    unsigned short* __restrict__ qkv)
{
    __shared__ __align__(16) unsigned short As[2][128 * 64];
    __shared__ __align__(16) unsigned short Bs[2][128 * 64];
    const int tid = threadIdx.x;
    const int lane = tid & 63, wave = tid >> 6;
    const int g = lane >> 4, c16 = lane & 15;
    // M-chunked XCD mapping: each XCD owns 4 bm x 24 bn
    const int xcd = blockIdx.x & 7, idx = blockIdx.x >> 3;
    const int bm = (xcd << 2) + idx / 24, bn = idx % 24;
    const int jbase = bn << 7;
    const int which = jbase >> 10;

    const int srow = wave * 32 + (lane >> 3);
    const int swc = ((lane & 7) ^ (lane >> 3)) << 3;   // pre-swizzled chunk
    const unsigned short* asrc = xb + ((size_t)(bm << 7) + srow) * C_ + swc;
    const unsigned short* bsrc = wb + ((size_t)(bn << 7) + srow) * C_ + swc;

    f32x4 acc[4][4];
#pragma unroll
    for (int i = 0; i < 4; i++)
#pragma unroll
        for (int j = 0; j < 4; j++) acc[i][j] = (f32x4){0.f, 0.f, 0.f, 0.f};

    const int wm = (wave >> 1) << 6, wn = (wave & 1) << 6;

    auto stage = [&](int buf, int k0) {
#pragma unroll
        for (int i = 0; i < 4; i++) {
            gll16(asrc + k0 + i * 8 * C_, &As[buf][(wave * 32 + i * 8) << 6]);
            gll16(bsrc + k0 + i * 8 * C_, &Bs[buf][(wave * 32 + i * 8) << 6]);
        }
    };

    stage(0, 0);
    int cur = 0;
    for (int t = 0; t < 16; ++t) {
        __syncthreads();                       // drains prev stage (vmcnt) + barrier
        if (t < 15) stage(cur ^ 1, (t + 1) << 6);
#pragma unroll
        for (int kk = 0; kk < 2; kk++) {
            bf16x8 af[4], bfv[4];
#pragma unroll
            for (int m = 0; m < 4; m++)
                af[m] = *reinterpret_cast<const bf16x8*>(
                    &As[cur][((wm + m * 16 + c16) << 6) + ((((kk << 2) + g) ^ (c16 & 7)) << 3)]);
#pragma unroll
            for (int n = 0; n < 4; n++)
                bfv[n] = *reinterpret_cast<const bf16x8*>(
                    &Bs[cur][((wn + n * 16 + c16) << 6) + ((((kk << 2) + g) ^ (c16 & 7)) << 3)]);
#pragma unroll
            for (int m = 0; m < 4; m++)
#pragma unroll
                for (int n = 0; n < 4; n++)
                    acc[m][n] = __builtin_amdgcn_mfma_f32_16x16x32_bf16(af[m], bfv[n], acc[m][n], 0, 0, 0);
        }
        cur ^= 1;
    }

    // epilogue: scatter to qkv[which][b][h][t][d]
#pragma unroll
    for (int m = 0; m < 4; m++) {
        const int grow = (bm << 7) + wm + m * 16 + (g << 2);
#pragma unroll
        for (int n = 0; n < 4; n++) {
            const int j = jbase + wn + n * 16 + c16;
            const int jj = j & 1023;
            const int h = jj >> 6, d = jj & 63;
#pragma unroll
            for (int r = 0; r < 4; r++) {
                const int row = grow + r;
                const int b = row >> 11, t = row & 2047;
                const size_t off = ((size_t)((which * B_ + b) * H_ + h) * T_ + t) * 64 + d;
                qkv[off] = bf1(acc[m][n][r]);
            }
        }
    }
}

// ---------------------------------------------------------------------------
// Kernel 2: causal flash attention, transposed (S^T / O^T) form.
// ---------------------------------------------------------------------------
__device__ __forceinline__ void attn_tile(
    const unsigned short* __restrict__ Ks, const unsigned short* __restrict__ Vt,
    unsigned short* __restrict__ Psw,
    const bf16x8& qf0, const bf16x8& qf1,
    float& m_run, float& l_run, f32x4* acc,
    int qglob, int s0, bool diag, int g, int c16)
{
    f32x4 sfT[4];
#pragma unroll
    for (int f = 0; f < 4; f++) sfT[f] = (f32x4){0.f, 0.f, 0.f, 0.f};

    __builtin_amdgcn_s_setprio(1);
#pragma unroll
    for (int f = 0; f < 4; f++) {
        const int row = f * 16 + c16;
        const int sw = row & 7;
        bf16x8 k0 = *reinterpret_cast<const bf16x8*>(&Ks[(row << 6) + ((g ^ sw) << 3)]);
        bf16x8 k1 = *reinterpret_cast<const bf16x8*>(&Ks[(row << 6) + (((g + 4) ^ sw) << 3)]);
        sfT[f] = __builtin_amdgcn_mfma_f32_16x16x32_bf16(k0, qf0, sfT[f], 0, 0, 0);
        sfT[f] = __builtin_amdgcn_mfma_f32_16x16x32_bf16(k1, qf1, sfT[f], 0, 0, 0);
    }
    __builtin_amdgcn_s_setprio(0);

    if (diag) {
#pragma unroll
        for (int f = 0; f < 4; f++)
#pragma unroll
            for (int r = 0; r < 4; r++) {
                const int kv = s0 + f * 16 + g * 4 + r;
                if (kv > qglob) sfT[f][r] = -1e30f;
            }
    }

    float mloc = -1e30f;
#pragma unroll
    for (int f = 0; f < 4; f++)
#pragma unroll
        for (int r = 0; r < 4; r++) mloc = fmaxf(mloc, sfT[f][r]);
    mloc = fmaxf(mloc, __shfl_xor(mloc, 16, 64));
    mloc = fmaxf(mloc, __shfl_xor(mloc, 32, 64));
    const float mn = fmaxf(m_run, mloc);
    const float corr = __builtin_amdgcn_exp2f(m_run - mn);
    m_run = mn;
    float ssum = 0.f;
#pragma unroll
    for (int f = 0; f < 4; f++)
#pragma unroll
        for (int r = 0; r < 4; r++) {
            const float pv = __builtin_amdgcn_exp2f(sfT[f][r] - mn);
            sfT[f][r] = pv;
            ssum += pv;
        }
    ssum += __shfl_xor(ssum, 16, 64);
    ssum += __shfl_xor(ssum, 32, 64);
    l_run = l_run * corr + ssum;
#pragma unroll
    for (int fd = 0; fd < 4; fd++)
#pragma unroll
        for (int r = 0; r < 4; r++) acc[fd][r] *= corr;

#pragma unroll
    for (int f = 0; f < 4; f++) {
        u32x2 w;
        w[0] = pk2(sfT[f][0], sfT[f][1]);
        w[1] = pk2(sfT[f][2], sfT[f][3]);
        *reinterpret_cast<u32x2*>(&Psw[c16 * 72 + f * 16 + g * 4]) = w;
    }

    __builtin_amdgcn_s_setprio(1);
#pragma unroll
    for (int ks = 0; ks < 2; ks++) {
        bf16x8 pa = *reinterpret_cast<const bf16x8*>(&Psw[c16 * 72 + ks * 32 + (g << 3)]);
#pragma unroll
        for (int fd = 0; fd < 4; fd++) {
            const int d = fd * 16 + c16;
            bf16x8 vf = *reinterpret_cast<const bf16x8*>(
                &Vt[d * 72 + ((((ks << 2) + g) ^ ((d >> 3) & 7)) << 3)]);
            acc[fd] = __builtin_amdgcn_mfma_f32_16x16x32_bf16(vf, pa, acc[fd], 0, 0, 0);
        }
    }
    __builtin_amdgcn_s_setprio(0);
}

__global__ __launch_bounds__(256) void attn(
    const unsigned short* __restrict__ qkv, unsigned short* __restrict__ y)
{
    __shared__ __align__(16) unsigned short Ks[64 * 64];
    __shared__ __align__(16) unsigned short Vt[64 * 72];
    __shared__ __align__(16) unsigned short Ps[4][16 * 72];
    const int tid = threadIdx.x, lane = tid & 63, wave = tid >> 6;
    const int g = lane >> 4, c16 = lane & 15;
    const int p = blockIdx.x & 15;
    const int bh = blockIdx.x >> 4;
    const int b = bh >> 4, h = bh & 15;
    const size_t headoff = (size_t)(b * H_ + h) * T_ * 64;
    const size_t QSZ = (size_t)B_ * H_ * T_ * 64;
    const unsigned short* qp = qkv + headoff;
    const unsigned short* kp = qkv + QSZ + headoff;
    const unsigned short* vp = qkv + 2 * QSZ + headoff;

    const int tA = p, tB = 31 - p;
    const int qbaseA = (tA << 6) + wave * 16, qbaseB = (tB << 6) + wave * 16;

    bf16x8 qfA[2], qfB[2];
    {
        const size_t ra = (size_t)(qbaseA + c16) * 64, rb = (size_t)(qbaseB + c16) * 64;
        qfA[0] = *reinterpret_cast<const bf16x8*>(qp + ra + g * 8);
        qfA[1] = *reinterpret_cast<const bf16x8*>(qp + ra + 32 + g * 8);
        qfB[0] = *reinterpret_cast<const bf16x8*>(qp + rb + g * 8);
        qfB[1] = *reinterpret_cast<const bf16x8*>(qp + rb + 32 + g * 8);
    }

    float mA = -1e30f, lA = 0.f, mB = -1e30f, lB = 0.f;
    f32x4 accA[4], accB[4];
#pragma unroll
    for (int i = 0; i < 4; i++) {
        accA[i] = (f32x4){0.f, 0.f, 0.f, 0.f};
        accB[i] = (f32x4){0.f, 0.f, 0.f, 0.f};
    }

    const int krow = tid >> 2, kc2 = (tid & 3) << 1;
    const int vr2 = (tid >> 3) << 1, vds = (tid & 7) << 3;

    const int nt = 32 - p;
    for (int it = 0; it < nt; ++it) {
        const int s0 = it << 6;
        __syncthreads();
        {
            const unsigned short* src = kp + (size_t)(s0 + krow) * 64 + (kc2 << 3);
            u16x8 a0 = *reinterpret_cast<const u16x8*>(src);
            u16x8 a1 = *reinterpret_cast<const u16x8*>(src + 8);
            const int sw = krow & 7;
            *reinterpret_cast<u16x8*>(&Ks[(krow << 6) + ((kc2 ^ sw) << 3)]) = a0;
            *reinterpret_cast<u16x8*>(&Ks[(krow << 6) + (((kc2 + 1) ^ sw) << 3)]) = a1;
        }
        {
            const unsigned short* sp = vp + (size_t)(s0 + vr2) * 64 + vds;
            u16x8 v0 = *reinterpret_cast<const u16x8*>(sp);
            u16x8 v1 = *reinterpret_cast<const u16x8*>(sp + 64);
#pragma unroll
            for (int i = 0; i < 8; i++) {
                const int d = vds + i;
                const unsigned int w = (unsigned int)v0[i] | ((unsigned int)v1[i] << 16);
                const int idx = d * 72 + ((((vr2 >> 3) ^ ((d >> 3) & 7)) << 3) | (vr2 & 7));
                *reinterpret_cast<unsigned int*>(&Vt[idx]) = w;
            }
        }
        __syncthreads();

        attn_tile(Ks, Vt, Ps[wave], qfB[0], qfB[1], mB, lB, accB,
                  qbaseB + c16, s0, it == tB, g, c16);
        if (it <= tA)
            attn_tile(Ks, Vt, Ps[wave], qfA[0], qfA[1], mA, lA, accA,
                      qbaseA + c16, s0, it == tA, g, c16);
    }

    const float liA = 1.0f / lA, liB = 1.0f / lB;
#pragma unroll
    for (int fd = 0; fd < 4; fd++) {
        u32x2 wa, wb2;
        wa[0] = pk2(accA[fd][0] * liA, accA[fd][1] * liA);
        wa[1] = pk2(accA[fd][2] * liA, accA[fd][3] * liA);
        wb2[0] = pk2(accB[fd][0] * liB, accB[fd][1] * liB);
        wb2[1] = pk2(accB[fd][2] * liB, accB[fd][3] * liB);
        const size_t ca = ((size_t)b * T_ + qbaseA + c16) * 1024 + h * 64 + fd * 16 + g * 4;
        const size_t cb = ((size_t)b * T_ + qbaseB + c16) * 1024 + h * 64 + fd * 16 + g * 4;
        *reinterpret_cast<u32x2*>(&y[ca]) = wa;
        *reinterpret_cast<u32x2*>(&y[cb]) = wb2;
    }
}

// ---------------------------------------------------------------------------
// Kernel 3: out[4096,1024] = y(bf16) @ wt^T(bf16), 2-phase double-buffer
// ---------------------------------------------------------------------------
__global__ __launch_bounds__(256) void out_proj(
    const unsigned short* __restrict__ y, const unsigned short* __restrict__ wt,
    float* __restrict__ out)
{
    __shared__ __align__(16) unsigned short As[2][128 * 64];
    __shared__ __align__(16) unsigned short Bs[2][128 * 64];
    const int tid = threadIdx.x;
    const int lane = tid & 63, wave = tid >> 6;
    const int g = lane >> 4, c16 = lane & 15;
    const int xcd = blockIdx.x & 7, idx = blockIdx.x >> 3;   // 256 = 8 * (4 bm * 8 bn)
    const int bm = (xcd << 2) + (idx >> 3), bn = idx & 7;
    const int wm = (wave >> 1) << 6, wn = (wave & 1) << 6;

    const int srow = wave * 32 + (lane >> 3);
    const int swc = ((lane & 7) ^ (lane >> 3)) << 3;
    const unsigned short* ysrc = y + ((size_t)(bm << 7) + srow) * 1024 + swc;
    const unsigned short* wsrc = wt + ((size_t)(bn << 7) + srow) * 1024 + swc;

    f32x4 acc[4][4];
#pragma unroll
    for (int i = 0; i < 4; i++)
#pragma unroll
        for (int j = 0; j < 4; j++) acc[i][j] = (f32x4){0.f, 0.f, 0.f, 0.f};

    auto stage = [&](int buf, int k0) {
#pragma unroll
        for (int i = 0; i < 4; i++) {
            gll16(ysrc + k0 + i * 8 * 1024, &As[buf][(wave * 32 + i * 8) << 6]);
            gll16(wsrc + k0 + i * 8 * 1024, &Bs[buf][(wave * 32 + i * 8) << 6]);
        }
    };

    stage(0, 0);
    int cur = 0;
    for (int t = 0; t < 16; ++t) {
        __syncthreads();
        if (t < 15) stage(cur ^ 1, (t + 1) << 6);
#pragma unroll
        for (int kk = 0; kk < 2; kk++) {
            bf16x8 af[4], bfr[4];
#pragma unroll
            for (int m = 0; m < 4; m++)
                af[m] = *reinterpret_cast<const bf16x8*>(
                    &As[cur][((wm + m * 16 + c16) << 6) + ((((kk << 2) + g) ^ (c16 & 7)) << 3)]);
#pragma unroll
            for (int n = 0; n < 4; n++)
                bfr[n] = *reinterpret_cast<const bf16x8*>(
                    &Bs[cur][((wn + n * 16 + c16) << 6) + ((((kk << 2) + g) ^ (c16 & 7)) << 3)]);
#pragma unroll
            for (int m = 0; m < 4; m++)
#pragma unroll
                for (int n = 0; n < 4; n++)
                    acc[m][n] = __builtin_amdgcn_mfma_f32_16x16x32_bf16(af[m], bfr[n], acc[m][n], 0, 0, 0);
        }
        cur ^= 1;
    }

#pragma unroll
    for (int m = 0; m < 4; m++) {
        const int grow = (bm << 7) + wm + m * 16 + (g << 2);
#pragma unroll
        for (int n = 0; n < 4; n++) {
            const int gcol = (bn << 7) + wn + n * 16 + c16;
#pragma unroll
            for (int r = 0; r < 4; r++)
                out[(size_t)(grow + r) * 1024 + gcol] = acc[m][n][r];
        }
    }
}

extern "C" void kernel_launch(void* const* d_in, const int* in_sizes, int n_in,
                              void* d_out, int out_size, void* d_ws, size_t ws_size,
                              hipStream_t stream) {
    const float* x  = (const float*)d_in[0];
    const float* wq = (const float*)d_in[1];
    const float* wk = (const float*)d_in[2];
    const float* wv = (const float*)d_in[3];
    const float* wo = (const float*)d_in[4];
    float* out = (float*)d_out;

    // ws layout (32 MB):
    //   [0,6MB)  wb   (dead after qkv_gemm)  -> y [0,8MB) reuses it (attn)
    //   [8,32MB) qkv  (dead after attn)      -> wt [8,10MB) reuses it (prep_wo)
    // d_out (16 MB f32): holds xb (8 MB bf16) until out_proj overwrites it.
    unsigned short* wb  = (unsigned short*)d_ws;
    unsigned short* y   = (unsigned short*)d_ws;
    unsigned short* qkv = (unsigned short*)d_ws + (size_t)4 * 1024 * 1024;
    unsigned short* wt  = qkv;
    unsigned short* xb  = (unsigned short*)d_out;

    prep_x<<<dim3(1024), 256, 0, stream>>>(x, xb);
    prep_w<<<dim3(768), 256, 0, stream>>>(wq, wk, wv, wb);
    qkv_gemm<<<dim3(768), 256, 0, stream>>>(xb, wb, qkv);
    attn<<<dim3(16 * B_ * H_), 256, 0, stream>>>(qkv, y);
    prep_wo<<<dim3(256), 256, 0, stream>>>(wo, wt);
    out_proj<<<dim3(256), 256, 0, stream>>>(y, wt, out);
}